// Round 9
// baseline (313.099 us; speedup 1.0000x reference)
//
#include <hip/hip_runtime.h>
#include <stdint.h>

#define OUT_F   2048
#define IN_BASE 2048
#define N_EMB   64
#define IN_TOT  2176   // 2048 + 128
#define NNZ_W   400000
#define NNZ_B   1024
#define BATCH   8192

typedef __bf16 bf16x8 __attribute__((ext_vector_type(8)));
typedef __bf16 bf16x4 __attribute__((ext_vector_type(4)));
typedef float  floatx16 __attribute__((ext_vector_type(16)));

#define AS1 __attribute__((address_space(1)))
#define AS3 __attribute__((address_space(3)))

// ---------------------------------------------------------------------------
// Kernel 1: build_x + COO binning + bias (r5 structure, verified ~8us).
// Round-6 lesson: do NOT fuse with GEMM (occupancy starvation, 370us fused).
// ---------------------------------------------------------------------------
#define NSEG     391                                // ceil(400000/1024)
#define SEG_NNZ  1024                               // nnz per pass-A block
#define CAP      24                                 // entries per (block,bin)
#define NBIN     256                                // bins = row>>3
#define BIN_ELEMS (8 * IN_TOT)                      // 17408 floats per slice

#define NB_SCAT  NSEG                               // blocks 0..390
#define NB_BIAS  2                                  // blocks 391..392
#define NB_BUILD BATCH                              // blocks 393..8584

__global__ void __launch_bounds__(512) prep_kernel(
    const float* __restrict__ x,
    const float* __restrict__ e0v, const int* __restrict__ e0p,
    const float* __restrict__ e1v, const int* __restrict__ e1p,
    __bf16* __restrict__ xb,
    const float* __restrict__ wv, const int* __restrict__ wr,
    const int* __restrict__ wc,
    const float* __restrict__ bv, const int* __restrict__ bi,
    float* __restrict__ segv, unsigned short* __restrict__ segm,
    unsigned char* __restrict__ segc,
    float* __restrict__ bfp)
{
    const int tid = threadIdx.x;
    const int blk = blockIdx.x;

    if (blk < NB_SCAT) {
        __shared__ unsigned int hist[NBIN];
        if (tid < NBIN) hist[tid] = 0;
        __syncthreads();
#pragma unroll
        for (int r = 0; r < 2; r++) {
            const int i = blk * SEG_NNZ + r * 512 + tid;
            if (i < NNZ_W) {
                const int row = wr[i], col = wc[i];
                const int bin = row >> 3;
                const unsigned int rank = atomicAdd(&hist[bin], 1u);
                if (rank < CAP) {   // overflow prob ~1e-9 (Poisson(4) tail)
                    const int p = (blk * NBIN + bin) * CAP + (int)rank;
                    segv[p] = wv[i];
                    segm[p] = (unsigned short)((row & 7) * IN_TOT + col);
                }
            }
        }
        __syncthreads();
        if (tid < NBIN)
            segc[blk * NBIN + tid] =
                (unsigned char)(hist[tid] < CAP ? hist[tid] : CAP);
    } else if (blk < NB_SCAT + NB_BIAS) {
        const int i = (blk - NB_SCAT) * 512 + tid;
        if (i < NNZ_B) unsafeAtomicAdd(bfp + bi[i], bv[i]);
    } else {
        const int b = blk - NB_SCAT - NB_BIAS;
        const float* xr = x + (size_t)b * IN_BASE;
        __bf16* xo = xb + (size_t)b * IN_TOT;

        {   // cols 0..2047: straight cast, 512 threads x 4 elems
            const float4 t = *(const float4*)(xr + tid * 4);
            bf16x4 o;
            o[0] = (__bf16)t.x; o[1] = (__bf16)t.y;
            o[2] = (__bf16)t.z; o[3] = (__bf16)t.w;
            *(bf16x4*)(xo + tid * 4) = o;
        }
        if (tid < 32) {      // cols 2048..2175 (embeds)
            const int g = 512 + tid;
            float v[4];
            if (g < 528) {                             // embed0: cols 2048..2111
                const int j = (g - 512) * 4;
#pragma unroll
                for (int t = 0; t < 4; t++) v[t] = e0v[j + t] * xr[e0p[j + t]];
            } else {                                   // embed1: cols 2112..2175
                const int j = (g - 528) * 4;
#pragma unroll
                for (int t = 0; t < 4; t++) {
                    const int p = e1p[j + t];
                    const float base = (p < IN_BASE)
                        ? xr[p]
                        : e0v[p - IN_BASE] * xr[e0p[p - IN_BASE]];
                    v[t] = e1v[j + t] * base;
                }
            }
            bf16x4 o;
            o[0] = (__bf16)v[0]; o[1] = (__bf16)v[1];
            o[2] = (__bf16)v[2]; o[3] = (__bf16)v[3];
            *(bf16x4*)(xo + g * 4) = o;
        }
    }
}

// ---------------------------------------------------------------------------
// Kernel 2: per-bin accumulate -> bf16 W (writes every slot; no W memset)
// ---------------------------------------------------------------------------
__global__ void __launch_bounds__(512) accum_kernel(
    const float* __restrict__ segv, const unsigned short* __restrict__ segm,
    const unsigned char* __restrict__ segc,
    __bf16* __restrict__ Wb)
{
    __shared__ float Ws[BIN_ELEMS];                 // 69,632 B
    const int tid = threadIdx.x;
    const int b   = blockIdx.x;                     // bin 0..255

    for (int e = tid; e < BIN_ELEMS; e += 512) Ws[e] = 0.f;
    __syncthreads();

    for (int s = tid; s < NSEG; s += 512) {
        const int c    = segc[s * NBIN + b];
        const int base = (s * NBIN + b) * CAP;
        for (int j = 0; j < c; j++)
            atomicAdd(&Ws[segm[base + j]], segv[base + j]);
    }
    __syncthreads();

    __bf16* wo = Wb + (size_t)b * BIN_ELEMS;
    for (int e = tid; e < BIN_ELEMS / 4; e += 512) {
        bf16x4 o;
        o[0] = (__bf16)Ws[e * 4 + 0]; o[1] = (__bf16)Ws[e * 4 + 1];
        o[2] = (__bf16)Ws[e * 4 + 2]; o[3] = (__bf16)Ws[e * 4 + 3];
        *(bf16x4*)(wo + e * 4) = o;
    }
}

// ---------------------------------------------------------------------------
// Kernel 3: GEMM  C[M,N] = A[M,K] * W[N,K]^T + bias   (K-major, "NT")
//
// ROUND-9: A DIRECT-FROM-GLOBAL (register fragments via L1), B via LDS.
// r7/r8 post-mortems + m233: the stage+vmcnt+LDS-drain complex for BOTH
// operands is the serial wall (~5530 cy/tile vs MFMA 2048); single-element
// removals (barriers r7, WAR hazards r8) are nulls.  The 4-way ds_read
// conflict is STRUCTURAL (gl_lds row-contiguous dest => bank = within-row
// offset => 32 lanes / 128B row >= 4-way).  So: remove A from LDS.
//
// A-frag for mfma_32x32x16 = 16 contiguous bytes per lane (row=l&31,
// k=khalf*8..+7) = one global_load_dwordx4.  A lines are k-tile aligned
// (4352 = 34*128) and reused 16x per block (4 wn-waves x 4 slices) -> L1
// (per-tile A slice = 256 lines = 32KB = L1 size).  HBM traffic unchanged.
// Removes 16/24 ds_reads per wave-tile, half the staging, sA entirely.
// Per-tile/CU: MFMA 2048 (matrix pipe) + B-LDS ~770 (DS pipe) + A ~1000
// (VMEM pipe) on three separate pipes, X/Y reg dbuf decoupling slices.
//
// B: 256x64 tile staged via 2x global_load_lds halves, 16B-chunk XOR
// swizzle (verified r3-r8), double-buffered (64 KiB), one VMW(0)+BAR per
// K-tile (A loads are consumed in-tile; drain only gates B staging).
// ---------------------------------------------------------------------------
#define BM 256
#define BN 256
#define BK 64
#define NKT (IN_TOT / BK)   // 34 K-tiles

#define CFENCE asm volatile("" ::: "memory")
#define BAR do { CFENCE; __builtin_amdgcn_s_barrier(); CFENCE; } while (0)
#define VMW(n) asm volatile("s_waitcnt vmcnt(" #n ")" ::: "memory")

// stage one B-half (128 rows x 64 k) of K-tile `tile` into buffer `buf`
#define STAGE_B(buf, tile, half) do {                                           \
    const __bf16* _s = Wg + (size_t)((half) * 128) * IN_TOT + (tile) * 64;      \
    char* _d = sBc + (buf) * 32768 + (half) * 16384 + tid * 16;                 \
    __builtin_amdgcn_global_load_lds((AS1 void*)(uintptr_t)_s,                  \
                                     (AS3 void*)_d, 16, 0, 0);                  \
    __builtin_amdgcn_global_load_lds((AS1 void*)(uintptr_t)(_s + (size_t)64 * IN_TOT), \
                                     (AS3 void*)(_d + 8192), 16, 0, 0);         \
} while (0)

// A fragments for slice ks of tile t: 4 direct global 16B loads (L1-resident)
#define RDA(as, t, ks) do {                                                     \
    as[0] = *(const bf16x8*)(Ap0 + (t) * 64 + (ks) * 16);                       \
    as[1] = *(const bf16x8*)(Ap1 + (t) * 64 + (ks) * 16);                       \
    as[2] = *(const bf16x8*)(Ap2 + (t) * 64 + (ks) * 16);                       \
    as[3] = *(const bf16x8*)(Ap3 + (t) * 64 + (ks) * 16);                       \
} while (0)

// B fragments for slice ks from LDS buffer pB: 2 ds_read_b128
#define RDB(bs, pB, ks) do {                                                    \
    const int kc = (ks) * 2 + khalf;                                            \
    _Pragma("unroll") for (int nq = 0; nq < 2; nq++) {                          \
        const int rb = nq * 128 + wn * 32 + l32;                                \
        bs[nq] = *(const bf16x8*)((pB) + rb * 64 + ((kc ^ (rb & 7)) * 8));      \
    }                                                                           \
} while (0)

// one slice's 8 MFMAs (4 A-frags x 2 B-frags)
#define MMS(as, bs) do {                                                        \
    _Pragma("unroll") for (int mq = 0; mq < 2; mq++)                            \
        _Pragma("unroll") for (int mi = 0; mi < 2; mi++)                        \
            _Pragma("unroll") for (int nq = 0; nq < 2; nq++)                    \
                acc[mq][mi][nq] = __builtin_amdgcn_mfma_f32_32x32x16_bf16(      \
                    as[mq * 2 + mi], bs[nq], acc[mq][mi][nq], 0, 0, 0);         \
} while (0)

// full K-tile: X/Y slice double-buffer, A from global, B from LDS buf
#define COMPUTE(buf, t) do {                                                    \
    const __bf16* _pB = sB + (buf) * 16384;                                     \
    RDA(aX, t, 0); RDB(bX, _pB, 0);                                             \
    RDA(aY, t, 1); RDB(bY, _pB, 1);                                             \
    MMS(aX, bX);                                                                \
    RDA(aX, t, 2); RDB(bX, _pB, 2);                                             \
    MMS(aY, bY);                                                                \
    RDA(aY, t, 3); RDB(bY, _pB, 3);                                             \
    MMS(aX, bX);                                                                \
    MMS(aY, bY);                                                                \
} while (0)

__global__ void __launch_bounds__(512, 2) gemm_kernel(
    const __bf16* __restrict__ A,   // [BATCH][IN_TOT]
    const __bf16* __restrict__ W,   // [OUT_F][IN_TOT]
    const float*  __restrict__ bias,
    float* __restrict__ C)          // [BATCH][OUT_F]
{
    __shared__ __align__(16) __bf16 sB[2 * 256 * 64];   // 64 KiB (2 bufs)

    const int tid   = threadIdx.x;
    const int bm    = blockIdx.x;    // M tile (32)
    const int bn    = blockIdx.y;    // N tile (8)
    const int wave  = tid >> 6;
    const int lane  = tid & 63;
    const int wm    = wave >> 2;     // 0..1
    const int wn    = wave & 3;      // 0..3
    const int l32   = lane & 31;
    const int khalf = lane >> 5;

    floatx16 acc[2][2][2] = {};      // [m quadrant][mi (32-row)][n quadrant]
    bf16x8 aX[4], bX[2];             // fragment set X (even slices)
    bf16x8 aY[4], bY[2];             // fragment set Y (odd slices)

    // per-lane A row pointers (khalf folded: +8 elems for upper k-half)
    const size_t rbase = (size_t)(bm * BM + wm * 64 + l32) * IN_TOT + khalf * 8;
    const __bf16* Ap0 = A + rbase;                            // mq0 mi0: +0
    const __bf16* Ap1 = A + rbase + (size_t) 32 * IN_TOT;     // mq0 mi1: +32
    const __bf16* Ap2 = A + rbase + (size_t)128 * IN_TOT;     // mq1 mi0: +128
    const __bf16* Ap3 = A + rbase + (size_t)160 * IN_TOT;     // mq1 mi1: +160

    // B staging: thread t -> row = t>>3 (x2 at +64), slot = t&7.
    // slot s of row r holds global chunk s ^ (r&7) => fetch chunk (t&7)^((t>>3)&7)
    const int srow   = tid >> 3;
    const int kchunk = ((tid & 7) ^ ((tid >> 3) & 7)) * 8;
    const __bf16* Wg = W + (size_t)(bn * BN + srow) * IN_TOT + kchunk;
    char* sBc = (char*)sB;

    // prologue: B tile0 -> buf0
    STAGE_B(0, 0, 0);
    STAGE_B(0, 0, 1);
    VMW(0);
    BAR;

#pragma unroll 1
    for (int t = 0; t < NKT - 1; ++t) {            // 33 iters
        const int cur = t & 1;
        STAGE_B(cur ^ 1, t + 1, 0);
        STAGE_B(cur ^ 1, t + 1, 1);
        COMPUTE(cur, t);
        VMW(0);
        BAR;
    }
    COMPUTE((NKT - 1) & 1, NKT - 1);               // tail tile 33

    // epilogue: C/D col = lane&31, row = (reg&3) + 8*(reg>>2) + 4*khalf  [verified]
#pragma unroll
    for (int m = 0; m < 2; m++)
#pragma unroll
    for (int mi = 0; mi < 2; mi++)
#pragma unroll
    for (int n = 0; n < 2; n++) {
        const int colg = bn * BN + n * 128 + wn * 32 + l32;
        const float bvv = bias[colg];
        const int rowb = bm * BM + m * 128 + wm * 64 + mi * 32 + 4 * khalf;
#pragma unroll
        for (int reg = 0; reg < 16; reg++) {
            const int rowg = rowb + (reg & 3) + 8 * (reg >> 2);
            C[(size_t)rowg * OUT_F + colg] = acc[m][mi][n][reg] + bvv;
        }
    }
}

// ---------------------------------------------------------------------------
// Launch
// ---------------------------------------------------------------------------
extern "C" void kernel_launch(void* const* d_in, const int* in_sizes, int n_in,
                              void* d_out, int out_size, void* d_ws, size_t ws_size,
                              hipStream_t stream) {
    const float* x      = (const float*)d_in[0];
    const float* w_vals = (const float*)d_in[1];
    const int*   w_rows = (const int*)  d_in[2];
    const int*   w_cols = (const int*)  d_in[3];
    const float* b_vals = (const float*)d_in[4];
    const int*   b_idx  = (const int*)  d_in[5];
    const float* e0v    = (const float*)d_in[6];
    const int*   e0p    = (const int*)  d_in[7];
    const float* e1v    = (const float*)d_in[8];
    const int*   e1p    = (const int*)  d_in[9];
    float* out = (float*)d_out;

    // workspace: Wb | bfp | xb | segv | segm | segc   (~59.1 MB)
    char* ws = (char*)d_ws;
    const size_t W_BF16_BYTES = (size_t)OUT_F * IN_TOT * 2;      //  8,912,896
    const size_t B_F32_BYTES  = (size_t)OUT_F * 4;               //      8,192
    const size_t XB_BYTES     = (size_t)BATCH * IN_TOT * 2;      // 35,651,584
    const size_t SEGV_BYTES   = (size_t)NSEG * NBIN * CAP * 4;   //  9,609,216
    const size_t SEGM_BYTES   = (size_t)NSEG * NBIN * CAP * 2;   //  4,804,608
    __bf16*         Wb   = (__bf16*)ws;
    float*          bfp  = (float*)(ws + W_BF16_BYTES);
    __bf16*         xb   = (__bf16*)(ws + W_BF16_BYTES + B_F32_BYTES);
    float*          segv = (float*)(ws + W_BF16_BYTES + B_F32_BYTES + XB_BYTES);
    unsigned short* segm = (unsigned short*)((char*)segv + SEGV_BYTES);
    unsigned char*  segc = (unsigned char*)((char*)segm + SEGM_BYTES);

    // only the bias accumulator needs zeroing (8 KB)
    hipMemsetAsync(bfp, 0, B_F32_BYTES, stream);

    prep_kernel<<<NB_SCAT + NB_BIAS + NB_BUILD, 512, 0, stream>>>(
        x, e0v, e0p, e1v, e1p, xb,
        w_vals, w_rows, w_cols, b_vals, b_idx,
        segv, segm, segc, bfp);

    accum_kernel<<<NBIN, 512, 0, stream>>>(segv, segm, segc, Wb);

    dim3 grid(BATCH / BM, OUT_F / BN);
    gemm_kernel<<<grid, 512, 0, stream>>>(xb, Wb, bfp, out);
}

// Round 10
// 270.886 us; speedup vs baseline: 1.1558x; 1.1558x over previous
//
#include <hip/hip_runtime.h>
#include <stdint.h>

#define OUT_F   2048
#define IN_BASE 2048
#define N_EMB   64
#define IN_TOT  2176   // 2048 + 128
#define NNZ_W   400000
#define NNZ_B   1024
#define BATCH   8192

typedef __bf16 bf16x8 __attribute__((ext_vector_type(8)));
typedef __bf16 bf16x4 __attribute__((ext_vector_type(4)));
typedef float  floatx16 __attribute__((ext_vector_type(16)));

#define AS1 __attribute__((address_space(1)))
#define AS3 __attribute__((address_space(3)))

// A shuffled layout: Ashuf[rg][kcpair][slot] of 16B chunks.
//   rg = row>>5 (256), kcpair = kc>>1 (136, kc = 8-elem chunk id 0..271),
//   slot = (row&31) | ((kc&1)<<5)  (64).
// A wave's A-fragment read = 64 consecutive slots = 1KB coalesced (8 lines),
// delivering the verified 32x32x16 A operand (row=l&31, k-half at lane 32).
// r9 lesson (measured): per-lane row-gather = 64 lines/instr = TA-fatal;
// this layout is the coalesced fix.
#define NKCP 136   // kcpairs per rg

// ---------------------------------------------------------------------------
// Kernel 1: build_x (shuffled-layout write) + COO binning + bias.
// Round-6 lesson: do NOT fuse with GEMM (occupancy starvation).
// ---------------------------------------------------------------------------
#define NSEG     391                                // ceil(400000/1024)
#define SEG_NNZ  1024
#define CAP      24
#define NBIN     256                                // bins = row>>3
#define BIN_ELEMS (8 * IN_TOT)                      // 17408 floats per slice

#define NB_SCAT  NSEG                               // blocks 0..390
#define NB_BIAS  2                                  // blocks 391..392
#define NB_BUILD BATCH                              // blocks 393..8584

__global__ void __launch_bounds__(512) prep_kernel(
    const float* __restrict__ x,
    const float* __restrict__ e0v, const int* __restrict__ e0p,
    const float* __restrict__ e1v, const int* __restrict__ e1p,
    __bf16* __restrict__ Ashuf,
    const float* __restrict__ wv, const int* __restrict__ wr,
    const int* __restrict__ wc,
    const float* __restrict__ bv, const int* __restrict__ bi,
    float* __restrict__ segv, unsigned short* __restrict__ segm,
    unsigned char* __restrict__ segc,
    float* __restrict__ bfp)
{
    const int tid = threadIdx.x;
    const int blk = blockIdx.x;

    if (blk < NB_SCAT) {
        __shared__ unsigned int hist[NBIN];
        if (tid < NBIN) hist[tid] = 0;
        __syncthreads();
#pragma unroll
        for (int r = 0; r < 2; r++) {
            const int i = blk * SEG_NNZ + r * 512 + tid;
            if (i < NNZ_W) {
                const int row = wr[i], col = wc[i];
                const int bin = row >> 3;
                const unsigned int rank = atomicAdd(&hist[bin], 1u);
                if (rank < CAP) {   // overflow prob ~1e-9 (Poisson(4) tail)
                    const int p = (blk * NBIN + bin) * CAP + (int)rank;
                    segv[p] = wv[i];
                    segm[p] = (unsigned short)((row & 7) * IN_TOT + col);
                }
            }
        }
        __syncthreads();
        if (tid < NBIN)
            segc[blk * NBIN + tid] =
                (unsigned char)(hist[tid] < CAP ? hist[tid] : CAP);
    } else if (blk < NB_SCAT + NB_BIAS) {
        const int i = (blk - NB_SCAT) * 512 + tid;
        if (i < NNZ_B) unsafeAtomicAdd(bfp + bi[i], bv[i]);
    } else {
        // ---- build_x: one row per block; thread kc<272 handles one 8-elem
        //      chunk; coalesced row read, shuffled 16B write ----
        const int b  = blk - NB_SCAT - NB_BIAS;
        const int kc = tid;
        if (kc < 272) {
            const float* xr = x + (size_t)b * IN_BASE;
            bf16x8 o;
            if (kc < 256) {                            // plain cols
                const float4 t0 = *(const float4*)(xr + kc * 8);
                const float4 t1 = *(const float4*)(xr + kc * 8 + 4);
                o[0] = (__bf16)t0.x; o[1] = (__bf16)t0.y;
                o[2] = (__bf16)t0.z; o[3] = (__bf16)t0.w;
                o[4] = (__bf16)t1.x; o[5] = (__bf16)t1.y;
                o[6] = (__bf16)t1.z; o[7] = (__bf16)t1.w;
            } else if (kc < 264) {                     // embed0: cols 2048..2111
                const int j0 = (kc - 256) * 8;
#pragma unroll
                for (int e = 0; e < 8; e++)
                    o[e] = (__bf16)(e0v[j0 + e] * xr[e0p[j0 + e]]);
            } else {                                   // embed1: cols 2112..2175
                const int j0 = (kc - 264) * 8;
#pragma unroll
                for (int e = 0; e < 8; e++) {
                    const int p = e1p[j0 + e];
                    const float base = (p < IN_BASE)
                        ? xr[p]
                        : e0v[p - IN_BASE] * xr[e0p[p - IN_BASE]];
                    o[e] = (__bf16)(e1v[j0 + e] * base);
                }
            }
            const int rg   = b >> 5;
            const int slot = (b & 31) | ((kc & 1) << 5);
            const size_t idx = ((size_t)(rg * NKCP + (kc >> 1)) * 64 + slot);
            *(bf16x8*)(Ashuf + idx * 8) = o;
        }
    }
}

// ---------------------------------------------------------------------------
// Kernel 2: per-bin accumulate -> bf16 W (writes every slot; no W memset)
// ---------------------------------------------------------------------------
__global__ void __launch_bounds__(512) accum_kernel(
    const float* __restrict__ segv, const unsigned short* __restrict__ segm,
    const unsigned char* __restrict__ segc,
    __bf16* __restrict__ Wb)
{
    __shared__ float Ws[BIN_ELEMS];                 // 69,632 B
    const int tid = threadIdx.x;
    const int b   = blockIdx.x;                     // bin 0..255

    for (int e = tid; e < BIN_ELEMS; e += 512) Ws[e] = 0.f;
    __syncthreads();

    for (int s = tid; s < NSEG; s += 512) {
        const int c    = segc[s * NBIN + b];
        const int base = (s * NBIN + b) * CAP;
        for (int j = 0; j < c; j++)
            atomicAdd(&Ws[segm[base + j]], segv[base + j]);
    }
    __syncthreads();

    __bf16* wo = Wb + (size_t)b * BIN_ELEMS;
    for (int e = tid; e < BIN_ELEMS / 4; e += 512) {
        bf16x4 o;
        o[0] = (__bf16)Ws[e * 4 + 0]; o[1] = (__bf16)Ws[e * 4 + 1];
        o[2] = (__bf16)Ws[e * 4 + 2]; o[3] = (__bf16)Ws[e * 4 + 3];
        *(bf16x4*)(wo + e * 4) = o;
    }
}

// ---------------------------------------------------------------------------
// Kernel 3: GEMM  C[M,N] = A[M,K] * W[N,K]^T + bias
//
// ROUND-10: A from SHUFFLED GLOBAL (coalesced 1KB/frag, L1-resident reuse
// x4 across wn-waves: 32KB/tile = L1), B via LDS (verified r3-r9 staging +
// 16B XOR swizzle, double-buffered 64KB), X/Y slice register double-buffer,
// one VMW(0)+BAR per K-tile.  Three independent pipes per tile/CU:
// MFMA 2065 cy (matrix) | B-LDS ~1030 cy (DS) | A ~1000-2000 cy (VMEM/L1),
// vs r7's single serialized LDS chain (5530 cy measured).
// ---------------------------------------------------------------------------
#define BM 256
#define BN 256
#define BK 64
#define NKT (IN_TOT / BK)   // 34 K-tiles

#define CFENCE asm volatile("" ::: "memory")
#define BAR do { CFENCE; __builtin_amdgcn_s_barrier(); CFENCE; } while (0)
#define VMW(n) asm volatile("s_waitcnt vmcnt(" #n ")" ::: "memory")

// stage one B-half (128 rows x 64 k) of K-tile `tile` into buffer `buf`
#define STAGE_B(buf, tile, half) do {                                           \
    const __bf16* _s = Wg + (size_t)((half) * 128) * IN_TOT + (tile) * 64;      \
    char* _d = sBc + (buf) * 32768 + (half) * 16384 + tid * 16;                 \
    __builtin_amdgcn_global_load_lds((AS1 void*)(uintptr_t)_s,                  \
                                     (AS3 void*)_d, 16, 0, 0);                  \
    __builtin_amdgcn_global_load_lds((AS1 void*)(uintptr_t)(_s + (size_t)64 * IN_TOT), \
                                     (AS3 void*)(_d + 8192), 16, 0, 0);         \
} while (0)

// A fragments for slice ks of tile t: 4 coalesced 1KB wave-loads (L1-hot)
#define RDA(as, t, ks) do {                                                     \
    const size_t _o = (size_t)((t) * 4 + (ks)) * 512;   /* elems */             \
    as[0] = *(const bf16x8*)(Ap0 + _o);                                         \
    as[1] = *(const bf16x8*)(Ap1 + _o);                                         \
    as[2] = *(const bf16x8*)(Ap2 + _o);                                         \
    as[3] = *(const bf16x8*)(Ap3 + _o);                                         \
} while (0)

// B fragments for slice ks from LDS buffer pB: 2 ds_read_b128
#define RDB(bs, pB, ks) do {                                                    \
    const int kc = (ks) * 2 + khalf;                                            \
    _Pragma("unroll") for (int nq = 0; nq < 2; nq++) {                          \
        const int rb = nq * 128 + wn * 32 + l32;                                \
        bs[nq] = *(const bf16x8*)((pB) + rb * 64 + ((kc ^ (rb & 7)) * 8));      \
    }                                                                           \
} while (0)

// one slice's 8 MFMAs (4 A-frags x 2 B-frags)
#define MMS(as, bs) do {                                                        \
    _Pragma("unroll") for (int mq = 0; mq < 2; mq++)                            \
        _Pragma("unroll") for (int mi = 0; mi < 2; mi++)                        \
            _Pragma("unroll") for (int nq = 0; nq < 2; nq++)                    \
                acc[mq][mi][nq] = __builtin_amdgcn_mfma_f32_32x32x16_bf16(      \
                    as[mq * 2 + mi], bs[nq], acc[mq][mi][nq], 0, 0, 0);         \
} while (0)

// full K-tile: X/Y slice double-buffer, A coalesced-global, B from LDS buf
#define COMPUTE(buf, t) do {                                                    \
    const __bf16* _pB = sB + (buf) * 16384;                                     \
    RDA(aX, t, 0); RDB(bX, _pB, 0);                                             \
    RDA(aY, t, 1); RDB(bY, _pB, 1);                                             \
    MMS(aX, bX);                                                                \
    RDA(aX, t, 2); RDB(bX, _pB, 2);                                             \
    MMS(aY, bY);                                                                \
    RDA(aY, t, 3); RDB(bY, _pB, 3);                                             \
    MMS(aX, bX);                                                                \
    MMS(aY, bY);                                                                \
} while (0)

__global__ void __launch_bounds__(512, 2) gemm_kernel(
    const __bf16* __restrict__ Ashuf,  // shuffled A, [256 rg][136 kcp][64 slot]x16B
    const __bf16* __restrict__ W,      // [OUT_F][IN_TOT]
    const float*  __restrict__ bias,
    float* __restrict__ C)             // [BATCH][OUT_F]
{
    __shared__ __align__(16) __bf16 sB[2 * 256 * 64];   // 64 KiB (2 bufs)

    const int tid   = threadIdx.x;
    const int bm    = blockIdx.x;    // M tile (32)
    const int bn    = blockIdx.y;    // N tile (8)
    const int wave  = tid >> 6;
    const int lane  = tid & 63;
    const int wm    = wave >> 2;     // 0..1
    const int wn    = wave & 3;      // 0..3
    const int l32   = lane & 31;
    const int khalf = lane >> 5;

    floatx16 acc[2][2][2] = {};      // [m quadrant][mi (32-row)][n quadrant]
    bf16x8 aX[4], bX[2];             // fragment set X (even slices)
    bf16x8 aY[4], bY[2];             // fragment set Y (odd slices)

    // A base pointers: frag j = mq*2+mi -> rg = bm*8 + mq*4 + wm*2 + mi
    const int rg0 = bm * 8 + wm * 2;
    const __bf16* Ap0 = Ashuf + ((size_t)((rg0 + 0) * NKCP) * 64 + lane) * 8;
    const __bf16* Ap1 = Ashuf + ((size_t)((rg0 + 1) * NKCP) * 64 + lane) * 8;
    const __bf16* Ap2 = Ashuf + ((size_t)((rg0 + 4) * NKCP) * 64 + lane) * 8;
    const __bf16* Ap3 = Ashuf + ((size_t)((rg0 + 5) * NKCP) * 64 + lane) * 8;

    // B staging: thread t -> row = t>>3 (x2 at +64), slot = t&7.
    const int srow   = tid >> 3;
    const int kchunk = ((tid & 7) ^ ((tid >> 3) & 7)) * 8;
    const __bf16* Wg = W + (size_t)(bn * BN + srow) * IN_TOT + kchunk;
    char* sBc = (char*)sB;

    // prologue: B tile0 -> buf0
    STAGE_B(0, 0, 0);
    STAGE_B(0, 0, 1);
    VMW(0);
    BAR;

#pragma unroll 1
    for (int t = 0; t < NKT - 1; ++t) {            // 33 iters
        const int cur = t & 1;
        STAGE_B(cur ^ 1, t + 1, 0);
        STAGE_B(cur ^ 1, t + 1, 1);
        COMPUTE(cur, t);
        VMW(0);                                    // A loads already consumed;
        BAR;                                       // this gates B staging only
    }
    COMPUTE((NKT - 1) & 1, NKT - 1);               // tail tile 33

    // epilogue: C/D col = lane&31, row = (reg&3) + 8*(reg>>2) + 4*khalf  [verified]
#pragma unroll
    for (int m = 0; m < 2; m++)
#pragma unroll
    for (int mi = 0; mi < 2; mi++)
#pragma unroll
    for (int n = 0; n < 2; n++) {
        const int colg = bn * BN + n * 128 + wn * 32 + l32;
        const float bvv = bias[colg];
        const int rowb = bm * BM + m * 128 + wm * 64 + mi * 32 + 4 * khalf;
#pragma unroll
        for (int reg = 0; reg < 16; reg++) {
            const int rowg = rowb + (reg & 3) + 8 * (reg >> 2);
            C[(size_t)rowg * OUT_F + colg] = acc[m][mi][n][reg] + bvv;
        }
    }
}

// ---------------------------------------------------------------------------
// Launch
// ---------------------------------------------------------------------------
extern "C" void kernel_launch(void* const* d_in, const int* in_sizes, int n_in,
                              void* d_out, int out_size, void* d_ws, size_t ws_size,
                              hipStream_t stream) {
    const float* x      = (const float*)d_in[0];
    const float* w_vals = (const float*)d_in[1];
    const int*   w_rows = (const int*)  d_in[2];
    const int*   w_cols = (const int*)  d_in[3];
    const float* b_vals = (const float*)d_in[4];
    const int*   b_idx  = (const int*)  d_in[5];
    const float* e0v    = (const float*)d_in[6];
    const int*   e0p    = (const int*)  d_in[7];
    const float* e1v    = (const float*)d_in[8];
    const int*   e1p    = (const int*)  d_in[9];
    float* out = (float*)d_out;

    // workspace: Wb | bfp | Ashuf | segv | segm | segc   (~59.1 MB)
    char* ws = (char*)d_ws;
    const size_t W_BF16_BYTES = (size_t)OUT_F * IN_TOT * 2;      //  8,912,896
    const size_t B_F32_BYTES  = (size_t)OUT_F * 4;               //      8,192
    const size_t A_BYTES      = (size_t)BATCH * IN_TOT * 2;      // 35,651,584
    const size_t SEGV_BYTES   = (size_t)NSEG * NBIN * CAP * 4;   //  9,609,216
    const size_t SEGM_BYTES   = (size_t)NSEG * NBIN * CAP * 2;   //  4,804,608
    __bf16*         Wb    = (__bf16*)ws;
    float*          bfp   = (float*)(ws + W_BF16_BYTES);
    __bf16*         Ashuf = (__bf16*)(ws + W_BF16_BYTES + B_F32_BYTES);
    float*          segv  = (float*)(ws + W_BF16_BYTES + B_F32_BYTES + A_BYTES);
    unsigned short* segm  = (unsigned short*)((char*)segv + SEGV_BYTES);
    unsigned char*  segc  = (unsigned char*)((char*)segm + SEGM_BYTES);

    // only the bias accumulator needs zeroing (8 KB)
    hipMemsetAsync(bfp, 0, B_F32_BYTES, stream);

    prep_kernel<<<NB_SCAT + NB_BIAS + NB_BUILD, 512, 0, stream>>>(
        x, e0v, e0p, e1v, e1p, Ashuf,
        w_vals, w_rows, w_cols, b_vals, b_idx,
        segv, segm, segc, bfp);

    accum_kernel<<<NBIN, 512, 0, stream>>>(segv, segm, segc, Wb);

    dim3 grid(BATCH / BM, OUT_F / BN);
    gemm_kernel<<<grid, 512, 0, stream>>>(Ashuf, Wb, bfp, out);
}